// Round 12
// baseline (291.499 us; speedup 1.0000x reference)
//
#include <hip/hip_runtime.h>
#include <hip/hip_bf16.h>

typedef __attribute__((ext_vector_type(8))) short bf16x8;
typedef __attribute__((ext_vector_type(4))) float f32x4;
typedef __attribute__((ext_vector_type(16))) float f32x16;
typedef __attribute__((ext_vector_type(4))) int i32x4;
typedef unsigned short u16;

__device__ __forceinline__ u16 f2bf(float f) {
    __hip_bfloat16 h = __float2bfloat16(f);
    return __builtin_bit_cast(u16, h);
}
__device__ __forceinline__ bf16x8 load8(const u16* p) {
    return *reinterpret_cast<const bf16x8*>(p);
}
__device__ __forceinline__ void gl2lds16(const u16* g, u16* l) {
    __builtin_amdgcn_global_load_lds(
        (const __attribute__((address_space(1))) void*)g,
        (__attribute__((address_space(3))) void*)l, 16, 0, 0);
}
// v_cvt_pk_bf16_f32: low16 = bf16(lo), high16 = bf16(hi)
__device__ __forceinline__ unsigned int cvtpk(float lo, float hi) {
    unsigned int r;
    asm("v_cvt_pk_bf16_f32 %0, %1, %2" : "=v"(r) : "v"(lo), "v"(hi));
    return r;
}

// log2(e)/8: folded into Q so softmax is exp2(s) with no per-element mul
#define QSCALE 0.1803368801111244f

// ---------------------------------------------------------------------------
// Merged cast kernel: x (2097152 f4) | w_qkv (786432 f4) | w_proj (262144 f4)
// ---------------------------------------------------------------------------
__global__ __launch_bounds__(256) void cast_all(
    const float* __restrict__ x, const float* __restrict__ wq,
    const float* __restrict__ wp, u16* __restrict__ Xb,
    u16* __restrict__ Wqb, u16* __restrict__ Wpb)
{
    int i = blockIdx.x * blockDim.x + threadIdx.x;
    const float* s; u16* d; int j;
    if (i < 2097152)      { s = x;  d = Xb;  j = i; }
    else if (i < 2883584) { s = wq; d = Wqb; j = i - 2097152; }
    else                  { s = wp; d = Wpb; j = i - 2883584; }
    float4 f = reinterpret_cast<const float4*>(s)[j];
    ushort4 o;
    o.x = f2bf(f.x); o.y = f2bf(f.y); o.z = f2bf(f.z); o.w = f2bf(f.w);
    reinterpret_cast<ushort4*>(d)[j] = o;
}

// ---------------------------------------------------------------------------
// 128x128-tile GEMM core (bf16, B^T layout W[n][k], K=1024, BK=32).
// 128 threads = 2 waves, N-split: per-wave output 128x64 (8x4 16x16 frags).
// Rationale: FLOP per LDS-byte = Mw*Nw/(Mw+Nw) = 42.7 for 128x64 vs 32 for
// 64x64 (= exactly the HW break-even 4069 FLOP/cyc / 128 B/cyc) -> ds_read
// no longer co-limits MFMA.  VGPR ~200 (acc 128 + frags 48) -> 2 waves/SIMD,
// 4 blocks/CU (LDS 32KB each): cross-block overlap covers barrier drains.
// Sync skeleton unchanged from the proven R10 loop: 1 barrier/iter,
// STAGE(ks+1) issued AFTER the barrier (one step ahead; the barrier only
// drains a full-iteration-old stage), setprio(1) around the MFMA cluster.
// LDS per buffer (u16): A[128 rows][32 k] @0 (4096), B[128][32] @4096.
// Dbuf = 16384 u16 = 32 KB dynamic.
// ---------------------------------------------------------------------------
#define STAGE_W(BASE, KK)                                                      \
    {                                                                          \
        _Pragma("unroll")                                                      \
        for (int g = 0; g < 4; ++g)                                            \
            gl2lds16(gA + (size_t)g * 32 * 1024 + (KK),                        \
                     (BASE) + g * 1024 + t * 8);                               \
        _Pragma("unroll")                                                      \
        for (int g = 0; g < 4; ++g)                                            \
            gl2lds16(gB + (size_t)g * 32 * 1024 + (KK),                        \
                     (BASE) + 4096 + g * 1024 + t * 8);                        \
    }

#define GEMMW_BODY(EPILOGUE)                                                   \
    const int t = threadIdx.x;                                                 \
    const int lane = t & 63;                                                   \
    const int wave = t >> 6;            /* 0..1 = N-half */                    \
    const int quad = lane >> 4;                                                \
    const int lid  = lane & 15;                                                \
    const int mtile = blockIdx.x * 128;                                        \
    const int ntile = blockIdx.y * 128;                                        \
    const int srow = t >> 2;                                                   \
    const int sk   = (t & 3) * 8;                                              \
    const u16* gA = Aptr + (size_t)(mtile + srow) * 1024 + sk;                 \
    const u16* gB = Bptr + (size_t)(ntile + srow) * 1024 + sk;                 \
    f32x4 acc[8][4] = {};                                                      \
    STAGE_W(smem, 0)                                                           \
    for (int ks = 0; ks < 32; ++ks) {                                          \
        u16* cb = smem + (ks & 1) * 8192;                                      \
        __syncthreads();                                                       \
        if (ks + 1 < 32) STAGE_W(smem + ((ks + 1) & 1) * 8192, (ks + 1) * 32)  \
        bf16x8 af[8], bfr[4];                                                  \
        _Pragma("unroll")                                                      \
        for (int mi = 0; mi < 8; ++mi)                                         \
            af[mi] = load8(cb + (mi * 16 + lid) * 32 + quad * 8);              \
        _Pragma("unroll")                                                      \
        for (int ni = 0; ni < 4; ++ni)                                         \
            bfr[ni] = load8(cb + 4096 +                                        \
                (wave * 64 + ni * 16 + lid) * 32 + quad * 8);                  \
        __builtin_amdgcn_s_setprio(1);                                         \
        _Pragma("unroll")                                                      \
        for (int mi = 0; mi < 8; ++mi)                                         \
            _Pragma("unroll")                                                  \
            for (int ni = 0; ni < 4; ++ni)                                     \
                acc[mi][ni] = __builtin_amdgcn_mfma_f32_16x16x32_bf16(         \
                    af[mi], bfr[ni], acc[mi][ni], 0, 0, 0);                    \
        __builtin_amdgcn_s_setprio(0);                                         \
    }                                                                          \
    EPILOGUE

// ---------------------------------------------------------------------------
// Kernel 1: QKV projection.  Q (pre-scaled by QSCALE), K -> [16][8192][64];
// V transposed -> Vt[16][64][8192] via an LDS transpose tile (reuses the
// staging LDS after the K-loop; 64 d x 130 m-pairs, dword stride 65 = 1
// mod 32 -> conflict-free).  A block's n-window is 128 wide, so its
// V-columns form a single <=64-wide run (runs are 192 apart): d uniquely
// indexes the tile and the run's h solves ntile <= h*192+128+d < ntile+128.
// ---------------------------------------------------------------------------
__global__ __launch_bounds__(128, 2) void qkv_gemmw(
    const u16* __restrict__ Aptr, const u16* __restrict__ Bptr,
    u16* __restrict__ Q, u16* __restrict__ K, u16* __restrict__ Vt)
{
    extern __shared__ u16 smem[];
    GEMMW_BODY(
    __syncthreads();   // all ds_reads of staging LDS done before reuse
    _Pragma("unroll")
    for (int mi = 0; mi < 8; ++mi)
        _Pragma("unroll")
        for (int ni = 0; ni < 4; ++ni)
            _Pragma("unroll")
            for (int r = 0; r < 4; ++r) {
                int ml = mi * 16 + quad * 4 + r;
                int m = mtile + ml;
                int n = ntile + wave * 64 + ni * 16 + lid;
                int h = n / 192;
                int rr = n - h * 192;
                int sel = rr >> 6;
                int d = rr & 63;
                float v = acc[mi][ni][r];
                if (sel == 2)
                    smem[d * 130 + ml] = f2bf(v);
                else if (sel == 0)
                    Q[((size_t)h * 8192 + m) * 64 + d] = f2bf(v * QSCALE);
                else
                    K[((size_t)h * 8192 + m) * 64 + d] = f2bf(v);
            }
    __syncthreads();
    for (int d = wave; d < 64; d += 2) {          // 2 waves x 32 rows
        int lo = ntile - 128 - d;                 // h*192 >= lo
        int hh = (lo + 191) / 192;                // lo >= -191 -> safe
        int n2 = hh * 192 + 128 + d;
        if (n2 >= ntile && n2 < ntile + 128 && hh < 16) {
            unsigned int w = (unsigned int)smem[d * 130 + lane * 2]
                           | ((unsigned int)smem[d * 130 + lane * 2 + 1] << 16);
            *reinterpret_cast<unsigned int*>(
                Vt + ((size_t)(hh * 64 + d)) * 8192 + mtile + lane * 2) = w;
        }
    }
    )
}

// ---------------------------------------------------------------------------
// Kernel 3: output projection, fp32 out + bias
// ---------------------------------------------------------------------------
__global__ __launch_bounds__(128, 2) void proj_gemmw(
    const u16* __restrict__ Aptr, const u16* __restrict__ Bptr,
    const float* __restrict__ bias, float* __restrict__ out)
{
    extern __shared__ u16 smem[];
    GEMMW_BODY(
    _Pragma("unroll")
    for (int mi = 0; mi < 8; ++mi)
        _Pragma("unroll")
        for (int ni = 0; ni < 4; ++ni)
            _Pragma("unroll")
            for (int r = 0; r < 4; ++r) {
                int m = mtile + mi * 16 + quad * 4 + r;
                int n = ntile + wave * 64 + ni * 16 + lid;
                out[(size_t)m * 1024 + n] = acc[mi][ni][r] + bias[n];
            }
    )
}

// ---------------------------------------------------------------------------
// Kernel 2: causal flash attention, 32x32 swapped-QK^T, in-register P.
// EXACT Round-5 code (proven 104.5 us).
// ---------------------------------------------------------------------------
__global__ __launch_bounds__(128, 4) void attn(
    const u16* __restrict__ Q, const u16* __restrict__ K,
    const u16* __restrict__ Vtg, u16* __restrict__ O)
{
    const int qt64 = 31 - (blockIdx.x >> 6);    // heavy-first
    const int bh = blockIdx.x & 63;             // bid%8==bh%8 -> XCD-local K/V
    const int b = bh >> 4, h = bh & 15;
    const int tid = threadIdx.x;
    const int lane = tid & 63;
    const int wave = tid >> 6;                  // 0..1
    const int c31 = lane & 31;
    const int ht  = lane >> 5;

    const size_t hb = ((size_t)h * 8192 + (size_t)b * 2048) * 64;
    const u16* Qp = Q + hb;
    const u16* Kp = K + hb;
    const u16* Vp = Vtg + (size_t)h * 64 * 8192 + (size_t)b * 2048;

    __shared__ __align__(16) u16 Vt[2][64 * 64];   // [d][key-chunk swizzled]

    // V^T staging (128 threads, 4 gl2lds/tile): thread covers d = vd+16g,
    // slot = tid&7; global chunk = slot ^ (d&7).  XOR swizzle on the
    // global-address side; LDS dest lane-linear per wave.
    const int vd = tid >> 3, vslot = tid & 7;
    const int vchunk = vslot ^ (vd & 7);
    const u16* vg = Vp + (size_t)vd * 8192 + vchunk * 8;
    u16* const ldst = (u16*)Vt[0] + vd * 64 + vslot * 8;   // + buf sel later

#define STAGE(BUFSEL, KK)                                                      \
    {                                                                          \
        u16* d_ = ldst + (BUFSEL) * 4096;                                      \
        _Pragma("unroll")                                                      \
        for (int g = 0; g < 4; ++g)                                            \
            gl2lds16(vg + (size_t)g * 16 * 8192 + (KK), d_ + g * 1024);        \
    }

    const int qw = qt64 * 64 + wave * 32;
    const int q  = qw + c31;        // this lane's q-row (same for both halves)

    bf16x8 qf[4];
#pragma unroll
    for (int dm = 0; dm < 4; ++dm)
        qf[dm] = load8(Qp + (size_t)q * 64 + dm * 16 + ht * 8);

    f32x16 od0 = {}, od1 = {};      // O^T accum: d 0..31 / 32..63
    float lsum = 0.f;

    const int nkt = qt64 + 1;

    // prologue: stage tile 0
    STAGE(0, 0)

#define SOFTMAX_KB(ST, KBOFF, PF0, PF1)                                        \
    {                                                                          \
        float pv[16];                                                          \
        _Pragma("unroll")                                                      \
        for (int r = 0; r < 16; ++r) {                                         \
            const int kg = k0 + (KBOFF) + (r & 3) + 8 * (r >> 2) + 4 * ht;     \
            float sv = ST[r];                                                  \
            if (needmask && kg > q) sv = -1e30f;                               \
            const float p = exp2f(sv);                                         \
            pv[r] = p;                                                         \
            lsum += p;                                                         \
        }                                                                      \
        _Pragma("unroll")                                                      \
        for (int a = 0; a < 2; ++a) {                                          \
            unsigned int u  = cvtpk(pv[8 * a + 0], pv[8 * a + 1]);             \
            unsigned int u2 = cvtpk(pv[8 * a + 2], pv[8 * a + 3]);             \
            unsigned int v  = cvtpk(pv[8 * a + 4], pv[8 * a + 5]);             \
            unsigned int v2 = cvtpk(pv[8 * a + 6], pv[8 * a + 7]);             \
            int r1 = __shfl_xor((int)(ht ? u : v), 32, 64);                    \
            int r2 = __shfl_xor((int)(ht ? u2 : v2), 32, 64);                  \
            i32x4 w;                                                           \
            w.x = ht ? r1 : (int)u;                                            \
            w.y = ht ? r2 : (int)u2;                                           \
            w.z = ht ? (int)v : r1;                                            \
            w.w = ht ? (int)v2 : r2;                                           \
            ((a) ? (PF1) : (PF0)) = __builtin_bit_cast(bf16x8, w);             \
        }                                                                      \
    }

    for (int kt = 0; kt < nkt; ++kt) {
        const int k0 = kt * 64;
        u16* vbuf = Vt[kt & 1];
        // upper key-half (k0+32..k0+63) fully masked? (wave0 diagonal tile)
        const bool skipB = (k0 >= qw);          // wave-uniform
        const bool needmask = (k0 + 63 > qw);   // wave-uniform
        bf16x8 pf[4];

        {
            bf16x8 kfA[4];
#pragma unroll
            for (int dm = 0; dm < 4; ++dm)
                kfA[dm] = load8(Kp + (size_t)(k0 + c31) * 64 + dm * 16 + ht * 8);
            f32x16 stA = {};
            __builtin_amdgcn_s_setprio(1);
#pragma unroll
            for (int dm = 0; dm < 4; ++dm)
                stA = __builtin_amdgcn_mfma_f32_32x32x16_bf16(kfA[dm], qf[dm], stA, 0, 0, 0);
            __builtin_amdgcn_s_setprio(0);
            SOFTMAX_KB(stA, 0, pf[0], pf[1]);
        }
        if (!skipB) {
            bf16x8 kfB[4];
#pragma unroll
            for (int dm = 0; dm < 4; ++dm)
                kfB[dm] = load8(Kp + (size_t)(k0 + 32 + c31) * 64 + dm * 16 + ht * 8);
            f32x16 stB = {};
            __builtin_amdgcn_s_setprio(1);
#pragma unroll
            for (int dm = 0; dm < 4; ++dm)
                stB = __builtin_amdgcn_mfma_f32_32x32x16_bf16(kfB[dm], qf[dm], stB, 0, 0, 0);
            __builtin_amdgcn_s_setprio(0);
            SOFTMAX_KB(stB, 32, pf[2], pf[3]);
        }

        // drains stage(kt) (issued one iter ago -> landed) and orders all
        // PV(kt-1) reads of buf[(kt+1)&1] before its overwrite
        __syncthreads();

        if (kt + 1 < nkt) STAGE((kt + 1) & 1, k0 + 64)

        __builtin_amdgcn_s_setprio(1);
#pragma unroll
        for (int km = 0; km < 4; ++km) {
            if (km >= 2 && skipB) continue;     // wave-uniform, static unroll
            const int sl = ((km * 2 + ht) ^ (c31 & 7)) * 8;
            bf16x8 v0 = load8(vbuf + c31 * 64 + sl);
            bf16x8 v1 = load8(vbuf + (32 + c31) * 64 + sl);
            od0 = __builtin_amdgcn_mfma_f32_32x32x16_bf16(v0, pf[km], od0, 0, 0, 0);
            od1 = __builtin_amdgcn_mfma_f32_32x32x16_bf16(v1, pf[km], od1, 0, 0, 0);
        }
        __builtin_amdgcn_s_setprio(0);
    }

    // row-sum: own 32 keys + partner half's 32 keys (same q)
    const float tot = lsum +
        __builtin_bit_cast(float, __shfl_xor(__builtin_bit_cast(int, lsum), 32, 64));
    const float inv = 1.0f / tot;

    const size_t orow = (size_t)(b * 2048 + q) * 1024 + h * 64;
#pragma unroll
    for (int tp = 0; tp < 8; ++tp) {
        const int r = 2 * tp;
        const int d = (r & 3) + 8 * (r >> 2) + 4 * ht;   // even -> u32-aligned
        unsigned int w0 = (unsigned int)f2bf(od0[r] * inv) |
                          ((unsigned int)f2bf(od0[r + 1] * inv) << 16);
        unsigned int w1 = (unsigned int)f2bf(od1[r] * inv) |
                          ((unsigned int)f2bf(od1[r + 1] * inv) << 16);
        *reinterpret_cast<unsigned int*>(const_cast<u16*>(O) + orow + d) = w0;
        *reinterpret_cast<unsigned int*>(const_cast<u16*>(O) + orow + 32 + d) = w1;
    }
#undef SOFTMAX_KB
#undef STAGE
}

// ---------------------------------------------------------------------------
// ws (88 MB): Q 16 | K 16 | Vt 16 | A2 16 | Xb 16 | Wqb 6 | Wpb 2
// ---------------------------------------------------------------------------
extern "C" void kernel_launch(void* const* d_in, const int* in_sizes, int n_in,
                              void* d_out, int out_size, void* d_ws, size_t ws_size,
                              hipStream_t stream) {
    const float* x      = (const float*)d_in[0];
    const float* w_qkv  = (const float*)d_in[1];
    const float* w_proj = (const float*)d_in[2];
    const float* b_proj = (const float*)d_in[3];
    float* out = (float*)d_out;

    u16* Q   = (u16*)d_ws;
    u16* K   = Q   + (size_t)16 * 8192 * 64;
    u16* Vt  = K   + (size_t)16 * 8192 * 64;       // [16][64][8192]
    u16* A2  = Vt  + (size_t)16 * 64 * 8192;
    u16* Xb  = A2  + (size_t)8192 * 1024;
    u16* Wqb = Xb  + (size_t)8192 * 1024;
    u16* Wpb = Wqb + (size_t)3072 * 1024;

    cast_all<<<dim3(12288), 256, 0, stream>>>(x, w_qkv, w_proj, Xb, Wqb, Wpb);

    qkv_gemmw<<<dim3(64, 24), 128, 32768, stream>>>(Xb, Wqb, Q, K, Vt);
    attn<<<dim3(2048), 128, 0, stream>>>(Q, K, Vt, A2);
    proj_gemmw<<<dim3(64, 8), 128, 32768, stream>>>(A2, Wpb, b_proj, out);
}